// Round 3
// baseline (176.397 us; speedup 1.0000x reference)
//
#include <hip/hip_runtime.h>
#include <hip/hip_bf16.h>

#define B_   64
#define NW_  256
#define H_   768

#define AB_    (0.1f / 768.0f)   // ALPHA*BETA
#define OMB_   0.9f              // 1 - BETA
#define K1_    0.1f
#define BP_    1.2f
#define AVDL_  50.0f

typedef __bf16 bf16x4 __attribute__((ext_vector_type(4)));
typedef __bf16 bf16x8 __attribute__((ext_vector_type(8)));
typedef float  f32x4  __attribute__((ext_vector_type(4)));

// ---------------------------------------------------------------------------
// 128x128-tile GEMM, fused score-partial epilogue.
// Grid: 256 blocks of 256 threads; blockIdx.x = t*64 + b so that XCD (id%8)
// = b%8: all 4 tiles of one batch co-resident on one XCD -> L2 serves the
// 2x tile redundancy, HBM sees each input line once.
// Wave w computes the 64x64 quadrant (qm=w>>1, qn=w&1) over FULL K=768.
// Raw (unmasked) bf16 staging; null masks applied in the epilogue
// (dot(mq*q, md*d) = mq*md*dot(q,d)).
// ---------------------------------------------------------------------------
__global__ __launch_bounds__(256, 1) void gemm_fused(
    const float* __restrict__ q_rep, const float* __restrict__ d_rep,
    const int* __restrict__ q_ids, const int* __restrict__ d_ids,
    const int* __restrict__ d_tfs,
    float* __restrict__ S, float* __restrict__ ws_dot)
{
    // Double-buffered bf16 tiles, rows padded to 40 (80 B stride: 16B-aligned,
    // <=2-way bank aliasing everywhere = free).
    __shared__ __align__(16) __bf16 As[2][128][40];   // 20 KB
    __shared__ __align__(16) __bf16 Bs[2][128][40];   // 20 KB
    __shared__ float mq_s[128];     // q null mask
    __shared__ float md_s[128];     // d null mask
    __shared__ float mdtf_s[128];   // md * tf

    const int tid  = threadIdx.x;
    const int wave = tid >> 6;
    const int lane = tid & 63;
    const int bid  = blockIdx.x;
    const int b    = bid & 63;
    const int t    = bid >> 6;          // tile 0..3
    const int m0   = (t & 1) * 128;
    const int n0   = (t >> 1) * 128;

    // Masks / md*tf into LDS (visible after first barrier).
    if (tid < 128) {
        int4 qa = *(const int4*)(q_ids + ((size_t)b * NW_ + m0 + tid) * 4);
        mq_s[tid] = (qa.x == 0 && qa.y == 0 && qa.z == 0 && qa.w == 0) ? 0.f : 1.f;
    } else {
        const int r = tid - 128;
        int4 da = *(const int4*)(d_ids + ((size_t)b * NW_ + n0 + r) * 4);
        float md = (da.x == 0 && da.y == 0 && da.z == 0 && da.w == 0) ? 0.f : 1.f;
        md_s[r]   = md;
        mdtf_s[r] = md * (float)d_tfs[(size_t)b * NW_ + n0 + r];
    }

    // Staging map: chunk = 128 rows x 32 floats. Instr i (0..3): thread t
    // covers row i*32 + (t>>3), 16B segment (t&7). Per wave-instruction:
    // 8 dense 128B row-segments -> full cache lines.
    const int srow = tid >> 3;          // 0..31
    const int sseg = tid & 7;           // 0..7
    const float* Abase = q_rep + ((size_t)b * NW_ + m0) * H_;
    const float* Bbase = d_rep + ((size_t)b * NW_ + n0) * H_;

    float4 ra[4], rb[4];
    auto loadg = [&](int kc) {
#pragma unroll
        for (int i = 0; i < 4; ++i) {
            const int row = i * 32 + srow;
            ra[i] = *(const float4*)(Abase + (size_t)row * H_ + kc * 32 + sseg * 4);
            rb[i] = *(const float4*)(Bbase + (size_t)row * H_ + kc * 32 + sseg * 4);
        }
    };
    auto stage = [&](int buf) {
#pragma unroll
        for (int i = 0; i < 4; ++i) {
            const int row = i * 32 + srow;
            bf16x4 va = { (__bf16)ra[i].x, (__bf16)ra[i].y,
                          (__bf16)ra[i].z, (__bf16)ra[i].w };
            *(bf16x4*)&As[buf][row][sseg * 4] = va;
            bf16x4 vb = { (__bf16)rb[i].x, (__bf16)rb[i].y,
                          (__bf16)rb[i].z, (__bf16)rb[i].w };
            *(bf16x4*)&Bs[buf][row][sseg * 4] = vb;
        }
    };

    f32x4 acc[4][4];
#pragma unroll
    for (int i = 0; i < 4; ++i)
#pragma unroll
        for (int j = 0; j < 4; ++j)
            acc[i][j] = (f32x4){0.f, 0.f, 0.f, 0.f};

    const int fr = lane & 15;
    const int fk = (lane >> 4) * 8;
    const int qm = wave >> 1;           // quadrant row
    const int qn = wave & 1;            // quadrant col

    loadg(0);
    stage(0);
    __syncthreads();

    for (int kc = 0; kc < 24; ++kc) {
        const int buf = kc & 1;
        if (kc < 23) loadg(kc + 1);     // in flight across frag reads + MFMA
        bf16x8 af[4], bfr[4];
#pragma unroll
        for (int t4 = 0; t4 < 4; ++t4) {
            af[t4]  = *(bf16x8*)&As[buf][qm * 64 + t4 * 16 + fr][fk];
            bfr[t4] = *(bf16x8*)&Bs[buf][qn * 64 + t4 * 16 + fr][fk];
        }
#pragma unroll
        for (int i = 0; i < 4; ++i)
#pragma unroll
            for (int j = 0; j < 4; ++j)
                acc[i][j] = __builtin_amdgcn_mfma_f32_16x16x32_bf16(
                    af[i], bfr[j], acc[i][j], 0, 0, 0);
        if (kc < 23) stage(buf ^ 1);    // vmcnt wait lands here
        __syncthreads();
    }

    // Epilogue: apply masks, store S from acc, reduce score partials in-reg.
    // C layout: col = lane&15, row = (lane>>4)*4 + reg.
    const int cn = lane & 15;
    const int qg = lane >> 4;
    float md_l[4], mdtf_l[4];
#pragma unroll
    for (int j = 0; j < 4; ++j) {
        const int c = qn * 64 + j * 16 + cn;
        md_l[j]   = md_s[c];
        mdtf_l[j] = mdtf_s[c];
    }
    float* Sbase = S + ((size_t)b * NW_ + m0 + qm * 64) * NW_ + n0 + qn * 64;

    float rs[16];
#pragma unroll
    for (int i = 0; i < 4; ++i)
#pragma unroll
        for (int r = 0; r < 4; ++r) {
            const int row = i * 16 + qg * 4 + r;
            const float mq = mq_s[qm * 64 + row];
            float s = 0.f;
#pragma unroll
            for (int j = 0; j < 4; ++j) {
                const float v = acc[i][j][r];
                Sbase[(size_t)row * NW_ + j * 16 + cn] = v * mq * md_l[j];
                s += v * mdtf_l[j];
            }
            rs[i * 4 + r] = s;          // mq applied in final kernel
        }
    // Reduce over the 16 lanes of each quad-group (rows identical there).
#pragma unroll
    for (int off = 1; off <= 8; off <<= 1)
#pragma unroll
        for (int e = 0; e < 16; ++e)
            rs[e] += __shfl_xor(rs[e], off);
    if (cn == 0) {
#pragma unroll
        for (int i = 0; i < 4; ++i)
#pragma unroll
            for (int r = 0; r < 4; ++r)
                atomicAdd(&ws_dot[(size_t)b * NW_ + m0 + qm * 64 + i * 16 + qg * 4 + r],
                          rs[i * 4 + r]);
    }
}

// ---------------------------------------------------------------------------
// Per-batch finisher: exact-match term from ids, BM25 ratio, final reduce.
// 64 blocks x 256 threads; thread t = query window q.
// ---------------------------------------------------------------------------
__global__ __launch_bounds__(256) void final_kernel(
    const float* __restrict__ ws_dot, const int* __restrict__ q_ids,
    const int* __restrict__ d_ids, const int* __restrict__ d_tfs,
    const float* __restrict__ qtw, float* __restrict__ out)
{
    __shared__ int4  dk_s[256];
    __shared__ float tf_s[256];
    __shared__ float red[4];

    const int b = blockIdx.x;
    const int t = threadIdx.x;
    const int wave = t >> 6;
    const int lane = t & 63;

    dk_s[t] = *(const int4*)(d_ids + ((size_t)b * NW_ + t) * 4);
    tf_s[t] = (float)d_tfs[(size_t)b * NW_ + t];
    __syncthreads();

    const int4 qk = *(const int4*)(q_ids + ((size_t)b * NW_ + t) * 4);
    float em = 0.f, dl = 0.f;
    for (int d = 0; d < 256; ++d) {     // dk_s[d]: same addr all lanes -> broadcast
        const int4 dk = dk_s[d];
        const float tf = tf_s[d];
        dl += tf;
        if (dk.x == qk.x && dk.y == qk.y && dk.z == qk.z && dk.w == qk.w)
            em += tf;
    }
    const float mq = (qk.x | qk.y | qk.z | qk.w) ? 1.f : 0.f;
    const float etdf = AB_ * mq * ws_dot[(size_t)b * NW_ + t] + OMB_ * em;
    const float c = K1_ * (1.f - BP_ + BP_ * dl / AVDL_);
    float val = qtw[(size_t)b * NW_ + t] * (etdf * (1.f + K1_)) / (etdf + c + 1e-8f);

#pragma unroll
    for (int off = 32; off; off >>= 1) val += __shfl_xor(val, off);
    if (lane == 0) red[wave] = val;
    __syncthreads();
    if (t == 0) out[b] = red[0] + red[1] + red[2] + red[3];
}

extern "C" void kernel_launch(void* const* d_in, const int* in_sizes, int n_in,
                              void* d_out, int out_size, void* d_ws, size_t ws_size,
                              hipStream_t stream)
{
    const float* q_rep = (const float*)d_in[0];
    const float* d_rep = (const float*)d_in[1];
    const float* qtw   = (const float*)d_in[2];
    const int*   q_ids = (const int*)d_in[3];
    const int*   d_ids = (const int*)d_in[4];
    const int*   d_tfs = (const int*)d_in[5];

    float* out = (float*)d_out;
    float* S   = out + B_;              // d_expanded_tf, [B, NW, NW]
    float* ws_dot = (float*)d_ws;       // [B, NW] f32

    hipMemsetAsync(ws_dot, 0, (size_t)B_ * NW_ * sizeof(float), stream);

    gemm_fused<<<256, 256, 0, stream>>>(q_rep, d_rep, q_ids, d_ids, d_tfs,
                                        S, ws_dot);
    final_kernel<<<B_, 256, 0, stream>>>(ws_dot, q_ids, d_ids, d_tfs, qtw, out);
}

// Round 4
// 165.785 us; speedup vs baseline: 1.0640x; 1.0640x over previous
//
#include <hip/hip_runtime.h>
#include <hip/hip_bf16.h>

#define B_   64
#define NW_  256
#define H_   768

#define ALPHA_BETA     (0.1f / 768.0f)   // ALPHA*BETA
#define OMB_           0.9f              // 1 - BETA
#define K1_            0.1f
#define BP_            1.2f
#define AVDL_          50.0f

typedef __bf16 bf16x8 __attribute__((ext_vector_type(8)));
typedef float  f32x4  __attribute__((ext_vector_type(4)));

// ---------------------------------------------------------------------------
// Fused GEMM + row-score kernel, XCD-pinned.
// Grid: 1024 blocks of 256 threads, bid = t*64 + b  (t = tile 0..15).
// XCD = bid % 8 = b % 8  ->  all 16 tiles of one batch on ONE XCD; the
// batch's 1.57 MB input slice fits the 4 MB XCD-L2, so the 4x tile
// redundancy is served by L2 and HBM sees each input byte once.
// Block = 4 waves, one 64x64 tile of S[b]; split-K inside the block
// (wave w: K-slice [w*192,(w+1)*192)), wave-PRIVATE LDS staging -> no
// barriers in the K-loop; 16 waves/CU hide global latency.
// ---------------------------------------------------------------------------
__global__ __launch_bounds__(256, 4) void gemm_score_kernel(
    const float* __restrict__ q_rep, const float* __restrict__ d_rep,
    const int* __restrict__ q_ids, const int* __restrict__ d_ids,
    const int* __restrict__ d_tfs,
    float* __restrict__ S, float* __restrict__ ws_etdf)
{
    // 40 KB LDS: 4 wave-private staging regions of 10 KB (A,B: 64 rows x
    // (32+8 pad) bf16 each). Epilogue aliases: T[64][68] f32 (17408 B) +
    // q keys (1 KB) + d keys (1 KB) + tf (256 B).
    __shared__ __align__(16) unsigned char lds[40960];

    const int tid  = threadIdx.x;
    const int wave = tid >> 6;
    const int lane = tid & 63;
    const int bid  = blockIdx.x;
    const int b    = bid & 63;          // batch -> XCD b%8
    const int t    = bid >> 6;          // tile 0..15
    const int m0   = (t & 3) * 64;
    const int n0   = (t >> 2) * 64;

    __bf16* As = (__bf16*)(lds + wave * 10240);          // [64][40]
    __bf16* Bs = As + 64 * 40;                           // [64][40]

    const int rq  = lane >> 2;          // 0..15: row within 16-row group
    const int seg = lane & 3;           // 0..3 : 8-float segment of BK=32

    // Null masks for the rows this lane stages (same rows every chunk).
    float mA[4], mB[4];
#pragma unroll
    for (int it = 0; it < 4; ++it) {
        const int row = it * 16 + rq;
        int4 qa = *(const int4*)(q_ids + ((size_t)b * NW_ + m0 + row) * 4);
        mA[it] = (qa.x == 0 && qa.y == 0 && qa.z == 0 && qa.w == 0) ? 0.f : 1.f;
        int4 da = *(const int4*)(d_ids + ((size_t)b * NW_ + n0 + row) * 4);
        mB[it] = (da.x == 0 && da.y == 0 && da.z == 0 && da.w == 0) ? 0.f : 1.f;
    }

    const float* Abase = q_rep + ((size_t)b * NW_ + m0) * H_ + wave * 192;
    const float* Bbase = d_rep + ((size_t)b * NW_ + n0) * H_ + wave * 192;

    f32x4 acc[4][4];
#pragma unroll
    for (int i = 0; i < 4; ++i)
#pragma unroll
        for (int j = 0; j < 4; ++j)
            acc[i][j] = (f32x4){0.f, 0.f, 0.f, 0.f};

    const int fr = lane & 15;           // frag row in 16x16 tile
    const int fk = (lane >> 4) * 8;     // frag k offset (quad*8)

    // K-loop: 6 chunks of 32 per wave. No __syncthreads inside — staging is
    // wave-private; compiler-inserted vmcnt/lgkmcnt give in-wave ordering.
    for (int kc = 0; kc < 6; ++kc) {
        float4 ra[8], rb[8];
#pragma unroll
        for (int it = 0; it < 4; ++it) {
            const float* pa = Abase + (size_t)(it * 16 + rq) * H_ + kc * 32 + seg * 8;
            ra[it * 2]     = *(const float4*)pa;
            ra[it * 2 + 1] = *(const float4*)(pa + 4);
            const float* pb = Bbase + (size_t)(it * 16 + rq) * H_ + kc * 32 + seg * 8;
            rb[it * 2]     = *(const float4*)pb;
            rb[it * 2 + 1] = *(const float4*)(pb + 4);
        }
#pragma unroll
        for (int it = 0; it < 4; ++it) {
            const int row = it * 16 + rq;
            float4 x = ra[it * 2], y = ra[it * 2 + 1];
            float m = mA[it];
            bf16x8 va;
            va[0] = (__bf16)(x.x * m); va[1] = (__bf16)(x.y * m);
            va[2] = (__bf16)(x.z * m); va[3] = (__bf16)(x.w * m);
            va[4] = (__bf16)(y.x * m); va[5] = (__bf16)(y.y * m);
            va[6] = (__bf16)(y.z * m); va[7] = (__bf16)(y.w * m);
            *(bf16x8*)&As[row * 40 + seg * 8] = va;

            float4 u = rb[it * 2], v = rb[it * 2 + 1];
            float n = mB[it];
            bf16x8 vb;
            vb[0] = (__bf16)(u.x * n); vb[1] = (__bf16)(u.y * n);
            vb[2] = (__bf16)(u.z * n); vb[3] = (__bf16)(u.w * n);
            vb[4] = (__bf16)(v.x * n); vb[5] = (__bf16)(v.y * n);
            vb[6] = (__bf16)(v.z * n); vb[7] = (__bf16)(v.w * n);
            *(bf16x8*)&Bs[row * 40 + seg * 8] = vb;
        }
        bf16x8 af[4], bfr[4];
#pragma unroll
        for (int t4 = 0; t4 < 4; ++t4) {
            af[t4]  = *(bf16x8*)&As[(t4 * 16 + fr) * 40 + fk];
            bfr[t4] = *(bf16x8*)&Bs[(t4 * 16 + fr) * 40 + fk];
        }
#pragma unroll
        for (int i = 0; i < 4; ++i)
#pragma unroll
            for (int j = 0; j < 4; ++j)
                acc[i][j] = __builtin_amdgcn_mfma_f32_16x16x32_bf16(
                    af[i], bfr[j], acc[i][j], 0, 0, 0);
    }

    __syncthreads();                    // all staging dead; begin epilogue

    float* T     = (float*)lds;                 // [64][68]
    int4*  qk_s  = (int4*)(lds + 17408);        // 64 q id-keys
    int4*  dk_s  = (int4*)(lds + 18432);        // 64 d id-keys
    float* tf_s  = (float*)(lds + 19456);       // 64 tf values

    if (tid < 64)
        qk_s[tid] = *(const int4*)(q_ids + ((size_t)b * NW_ + m0 + tid) * 4);
    else if (tid < 128)
        dk_s[tid - 64] = *(const int4*)(d_ids + ((size_t)b * NW_ + n0 + tid - 64) * 4);
    else if (tid < 192)
        tf_s[tid - 128] = (float)d_tfs[(size_t)b * NW_ + n0 + tid - 128];

    // Serialized cross-wave combine of the 4 K-slice partials.
    const int cn  = lane & 15;
    const int rb4 = (lane >> 4) * 4;
    for (int w = 0; w < 4; ++w) {
        if (wave == w) {
#pragma unroll
            for (int i = 0; i < 4; ++i)
#pragma unroll
                for (int j = 0; j < 4; ++j)
#pragma unroll
                    for (int r = 0; r < 4; ++r) {
                        const int row = i * 16 + rb4 + r;
                        const int col = j * 16 + cn;
                        if (w == 0) T[row * 68 + col]  = acc[i][j][r];
                        else        T[row * 68 + col] += acc[i][j][r];
                    }
        }
        __syncthreads();
    }

    // Store S (coalesced float4) and accumulate per-q score partials.
    const int r  = tid >> 2;            // 0..63: row within tile
    const int qq = tid & 3;             // quarter of the 64 cols
    const float* Tr = &T[r * 68 + qq * 16];
    float* Srow = S + ((size_t)b * NW_ + m0 + r) * NW_ + n0 + qq * 16;
#pragma unroll
    for (int i = 0; i < 4; ++i)
        ((float4*)Srow)[i] = ((const float4*)Tr)[i];

    int4 qk = qk_s[r];
    float ps = 0.f;
#pragma unroll
    for (int i = 0; i < 16; ++i) {
        const int c = qq * 16 + i;
        int4 dk = dk_s[c];
        float em = (dk.x == qk.x && dk.y == qk.y &&
                    dk.z == qk.z && dk.w == qk.w) ? OMB_ : 0.f;
        ps += (ALPHA_BETA * Tr[i] + em) * tf_s[c];
    }
    ps += __shfl_xor(ps, 1);
    ps += __shfl_xor(ps, 2);
    if (qq == 0)
        atomicAdd(&ws_etdf[(size_t)b * NW_ + m0 + r], ps);
}

// ---------------------------------------------------------------------------
// Final: per batch, dl = sum(tf); dtw = 1.1*etdf/(etdf + K1*(1-Bp+Bp*dl/AVDL)
// + 1e-8); s[b] = sum_q qtw*dtw.  One wave per batch.
// ---------------------------------------------------------------------------
__global__ __launch_bounds__(64) void final_kernel(
    const float* __restrict__ ws_etdf, const int* __restrict__ d_tfs,
    const float* __restrict__ qtw, float* __restrict__ out)
{
    const int b = blockIdx.x;
    const int lane = threadIdx.x;

    float4 ev = *(const float4*)(ws_etdf + (size_t)b * NW_ + lane * 4);
    int4  tf4 = *(const int4*)(d_tfs   + (size_t)b * NW_ + lane * 4);
    float4 qv = *(const float4*)(qtw    + (size_t)b * NW_ + lane * 4);

    float dl = (float)(tf4.x + tf4.y + tf4.z + tf4.w);
#pragma unroll
    for (int off = 32; off; off >>= 1) dl += __shfl_xor(dl, off);

    const float c = K1_ * (1.f - BP_ + BP_ * dl / AVDL_);
    float ew[4] = {ev.x, ev.y, ev.z, ev.w};
    float qw[4] = {qv.x, qv.y, qv.z, qv.w};
    float s = 0.f;
#pragma unroll
    for (int j = 0; j < 4; ++j)
        s += qw[j] * (ew[j] * (1.f + K1_)) / (ew[j] + c + 1e-8f);
#pragma unroll
    for (int off = 32; off; off >>= 1) s += __shfl_xor(s, off);
    if (lane == 0) out[b] = s;
}

extern "C" void kernel_launch(void* const* d_in, const int* in_sizes, int n_in,
                              void* d_out, int out_size, void* d_ws, size_t ws_size,
                              hipStream_t stream)
{
    const float* q_rep = (const float*)d_in[0];
    const float* d_rep = (const float*)d_in[1];
    const float* qtw   = (const float*)d_in[2];
    const int*   q_ids = (const int*)d_in[3];
    const int*   d_ids = (const int*)d_in[4];
    const int*   d_tfs = (const int*)d_in[5];

    float* out = (float*)d_out;
    float* S   = out + B_;              // d_expanded_tf, [B, NW, NW]
    float* ws_etdf = (float*)d_ws;      // [B, NW] f32 = 64 KiB scratch

    hipMemsetAsync(ws_etdf, 0, (size_t)B_ * NW_ * sizeof(float), stream);

    gemm_score_kernel<<<1024, 256, 0, stream>>>(q_rep, d_rep, q_ids, d_ids,
                                                d_tfs, S, ws_etdf);

    final_kernel<<<B_, 64, 0, stream>>>(ws_etdf, d_tfs, qtw, out);
}